// Round 6
// baseline (732.840 us; speedup 1.0000x reference)
//
#include <hip/hip_runtime.h>

#define T_SEQ 2048
#define C_DIM 1024
#define H_N   16
#define HS_D  64
#define V_DIM 32000

typedef float f32x4 __attribute__((ext_vector_type(4)));
typedef __bf16 bf16x8 __attribute__((ext_vector_type(8)));
typedef unsigned short us4 __attribute__((ext_vector_type(4)));
typedef unsigned short us8 __attribute__((ext_vector_type(8)));

__device__ inline unsigned short f2bf(float f) {
  unsigned int u = __float_as_uint(f);
  u = (u + 0x7FFFu + ((u >> 16) & 1u)) >> 16;
  return (unsigned short)u;
}

// ---------------- embed: h = tok_emb[x] + pos_emb, cast to bf16 ----------------
__global__ __launch_bounds__(256) void embed_kernel(
    const int* __restrict__ x, const float* __restrict__ tok,
    const float* __restrict__ pos, unsigned short* __restrict__ h) {
  int idx = blockIdx.x * 256 + threadIdx.x;   // over (B*T*C)/4
  int bt = idx >> 8;                          // 256 float4 per row
  int c4 = (idx & 255) * 4;
  int t = bt & (T_SEQ - 1);
  int tokid = x[bt];
  f32x4 a = *(const f32x4*)(tok + (size_t)tokid * C_DIM + c4);
  f32x4 b = *(const f32x4*)(pos + (size_t)t * C_DIM + c4);
  f32x4 s = a + b;
  us4 o;
  o[0] = f2bf(s[0]); o[1] = f2bf(s[1]); o[2] = f2bf(s[2]); o[3] = f2bf(s[3]);
  *(us4*)(h + (size_t)bt * C_DIM + c4) = o;
}

// ------------- repack wq/wk/wv [H,C,HS] f32 -> bf16 [3072][1024] (N,K) -------------
__global__ __launch_bounds__(256) void repack_qkv(
    const float* __restrict__ wq, const float* __restrict__ wk, const float* __restrict__ wv,
    const float* __restrict__ bq, const float* __restrict__ bk, const float* __restrict__ bv,
    unsigned short* __restrict__ wt, float* __restrict__ biasp) {
  int which = blockIdx.y;
  const float* w = (which == 0) ? wq : (which == 1) ? wk : wv;
  int i = blockIdx.x * 256 + threadIdx.x;   // 0 .. H*C*HS (=1M)
  int d = i & 63;
  int c = (i >> 6) & (C_DIM - 1);
  int hh = i >> 16;
  int n = which * 1024 + hh * 64 + d;
  wt[(size_t)n * C_DIM + c] = f2bf(w[i]);
  if (c == 0) {
    const float* bb = (which == 0) ? bq : (which == 1) ? bk : bv;
    biasp[n] = bb[hh * 64 + d];
  }
}

// ------------- transpose-repack w_head [C,V] f32 -> bf16 [V][C] -------------
__global__ __launch_bounds__(256) void repack_whead(
    const float* __restrict__ wh, unsigned short* __restrict__ wht) {
  __shared__ float tile[64][65];
  int v0 = blockIdx.x * 64;
  int c0 = blockIdx.y * 64;
  int tr = threadIdx.x >> 6;      // 0..3
  int tc = threadIdx.x & 63;
#pragma unroll
  for (int i = 0; i < 16; ++i) {
    int r = i * 4 + tr;
    tile[r][tc] = wh[(size_t)(c0 + r) * V_DIM + v0 + tc];
  }
  __syncthreads();
#pragma unroll
  for (int i = 0; i < 16; ++i) {
    int vr = i * 4 + tr;
    wht[(size_t)(v0 + vr) * C_DIM + c0 + tc] = f2bf(tile[tc][vr]);
  }
}

// ------------- 256x256 double-buffered 4-phase GEMM (race-free stagger) -------------
// C[M][N] = A[M][1024](bf16) x Bt[N][1024](bf16) + bias[N], f32 out.
// 8 waves (2M x 4N), BK=64. Phases read: P1 A-mh0+B-nh0, P2 B-nh1, P3 A-mh1, P4 none.
// Stage plan (1 half-region = 2 loads/thread per phase), each target consumed >=1
// closing-barrier earlier:
//   (t,P1) -> B-nh1(t+1) [other buf]     (t,P2) -> A-mh0(t+2) [same buf, dead since P1]
//   (t,P3) -> B-nh0(t+2) [dead since P1] (t,P4) -> A-mh1(t+2) [dead since P3]
// Waits placed BEFORE the closing barrier (cross-wave landing = wait+barrier):
//   P1end vmcnt(8), P2end vmcnt(12), P4end vmcnt(10); tail tiles 10/4/0. Never 0 mid-loop.
#define GK 1024
#define GNT 16   // K / 64

__global__ __launch_bounds__(512, 1) void gemm256(
    const unsigned short* __restrict__ A, const unsigned short* __restrict__ Bt,
    const float* __restrict__ bias, float* __restrict__ Cout, int N, int Mtiles) {
  __shared__ unsigned short As[2][256 * 64];
  __shared__ unsigned short Bs[2][256 * 64];
  int tid = threadIdx.x;
  int lane = tid & 63;
  int wid = tid >> 6;
  int wm = wid >> 2, wn = wid & 3;
  int l16 = lane & 15, g = lane >> 4;
  int swz = l16 & 7;

  // XCD-bijective swizzle (gridDim.x % 8 == 0); m-tile fastest for B-panel reuse
  int cpx = gridDim.x >> 3;
  int lin = blockIdx.x;
  int wg = (lin & 7) * cpx + (lin >> 3);
  int m0 = (wg % Mtiles) * 256;
  int n0 = (wg / Mtiles) * 256;

  // stage A half-region mh of K-tile kt: rows {mh*64+(0..63)} u {128+mh*64+(0..63)}
  auto stageA2 = [&](int kt, int mh) {
    unsigned short* lds = As[kt & 1];
#pragma unroll
    for (int q = 0; q < 2; ++q) {
      int chunk = q * 512 + tid;          // 0..1023
      int rr = chunk >> 3;
      int row = (rr & 63) + ((rr >> 6) << 7) + mh * 64;
      int cpos = chunk & 7;
      int c = cpos ^ (row & 7);           // inverse swizzle on global source
      const unsigned short* src = A + (size_t)(m0 + row) * GK + kt * 64 + c * 8;
      __builtin_amdgcn_global_load_lds(
          (const __attribute__((address_space(1))) void*)src,
          (__attribute__((address_space(3))) void*)(lds + row * 64 + cpos * 8), 16, 0, 0);
    }
  };
  // stage B half-region nh of K-tile kt: rows {q64*64 + nh*32 + (0..31)}
  auto stageB2 = [&](int kt, int nh) {
    unsigned short* lds = Bs[kt & 1];
#pragma unroll
    for (int q = 0; q < 2; ++q) {
      int chunk = q * 512 + tid;
      int rr = chunk >> 3;
      int row = (rr & 31) + ((rr >> 5) << 6) + nh * 32;
      int cpos = chunk & 7;
      int c = cpos ^ (row & 7);
      const unsigned short* src = Bt + (size_t)(n0 + row) * GK + kt * 64 + c * 8;
      __builtin_amdgcn_global_load_lds(
          (const __attribute__((address_space(1))) void*)src,
          (__attribute__((address_space(3))) void*)(lds + row * 64 + cpos * 8), 16, 0, 0);
    }
  };

  // prologue in steady-state FIFO order (7 stages = 14 loads)
  stageA2(0, 0); stageB2(0, 0); stageA2(0, 1); stageB2(0, 1);
  stageA2(1, 0); stageB2(1, 0); stageA2(1, 1);
  asm volatile("s_waitcnt vmcnt(10)" ::: "memory");   // A-mh0(0), B-nh0(0) landed
  asm volatile("s_barrier" ::: "memory");

  f32x4 acc[8][4] = {};

  for (int t = 0; t < GNT; ++t) {
    const char* Ab = (const char*)As[t & 1];
    const char* Bb = (const char*)Bs[t & 1];
    bf16x8 bA[4][2], bB0[2][2], bB1[2][2];

    // ================= P1: quadrant (0,0); reads A-mh0 + B-nh0 =================
#pragma unroll
    for (int mi = 0; mi < 4; ++mi) {
      int row = wm * 128 + mi * 16 + l16;
#pragma unroll
      for (int kk = 0; kk < 2; ++kk)
        bA[mi][kk] = *(const bf16x8*)(Ab + row * 128 + (((kk * 4 + g) ^ swz) * 16));
    }
#pragma unroll
    for (int ni = 0; ni < 2; ++ni) {
      int row = wn * 64 + ni * 16 + l16;
#pragma unroll
      for (int kk = 0; kk < 2; ++kk)
        bB0[ni][kk] = *(const bf16x8*)(Bb + row * 128 + (((kk * 4 + g) ^ swz) * 16));
    }
    if (t + 1 < GNT) stageB2(t + 1, 1);
    asm volatile("s_barrier" ::: "memory");
    asm volatile("s_waitcnt lgkmcnt(0)" ::: "memory");
    __builtin_amdgcn_s_setprio(1);
#pragma unroll
    for (int mi = 0; mi < 4; ++mi)
#pragma unroll
      for (int ni = 0; ni < 2; ++ni)
#pragma unroll
        for (int kk = 0; kk < 2; ++kk)
          acc[mi][ni] = __builtin_amdgcn_mfma_f32_16x16x32_bf16(bA[mi][kk], bB0[ni][kk], acc[mi][ni], 0, 0, 0);
    __builtin_amdgcn_s_setprio(0);
    if (t < GNT - 1) asm volatile("s_waitcnt vmcnt(8)" ::: "memory");
    else             asm volatile("s_waitcnt vmcnt(0)" ::: "memory");
    asm volatile("s_barrier" ::: "memory");

    // ================= P2: quadrant (0,1); reads B-nh1 =================
#pragma unroll
    for (int ni = 0; ni < 2; ++ni) {
      int row = wn * 64 + 32 + ni * 16 + l16;
#pragma unroll
      for (int kk = 0; kk < 2; ++kk)
        bB1[ni][kk] = *(const bf16x8*)(Bb + row * 128 + (((kk * 4 + g) ^ swz) * 16));
    }
    if (t + 2 < GNT) stageA2(t + 2, 0);
    asm volatile("s_barrier" ::: "memory");
    asm volatile("s_waitcnt lgkmcnt(0)" ::: "memory");
    __builtin_amdgcn_s_setprio(1);
#pragma unroll
    for (int mi = 0; mi < 4; ++mi)
#pragma unroll
      for (int ni = 0; ni < 2; ++ni)
#pragma unroll
        for (int kk = 0; kk < 2; ++kk)
          acc[mi][2 + ni] = __builtin_amdgcn_mfma_f32_16x16x32_bf16(bA[mi][kk], bB1[ni][kk], acc[mi][2 + ni], 0, 0, 0);
    __builtin_amdgcn_s_setprio(0);
    if (t < GNT - 2)       asm volatile("s_waitcnt vmcnt(12)" ::: "memory");
    else if (t == GNT - 2) asm volatile("s_waitcnt vmcnt(10)" ::: "memory");
    asm volatile("s_barrier" ::: "memory");

    // ================= P3: quadrant (1,1); reads A-mh1 =================
#pragma unroll
    for (int mi = 0; mi < 4; ++mi) {
      int row = wm * 128 + 64 + mi * 16 + l16;
#pragma unroll
      for (int kk = 0; kk < 2; ++kk)
        bA[mi][kk] = *(const bf16x8*)(Ab + row * 128 + (((kk * 4 + g) ^ swz) * 16));
    }
    if (t + 2 < GNT) stageB2(t + 2, 0);
    asm volatile("s_barrier" ::: "memory");
    asm volatile("s_waitcnt lgkmcnt(0)" ::: "memory");
    __builtin_amdgcn_s_setprio(1);
#pragma unroll
    for (int mi = 0; mi < 4; ++mi)
#pragma unroll
      for (int ni = 0; ni < 2; ++ni)
#pragma unroll
        for (int kk = 0; kk < 2; ++kk)
          acc[4 + mi][2 + ni] = __builtin_amdgcn_mfma_f32_16x16x32_bf16(bA[mi][kk], bB1[ni][kk], acc[4 + mi][2 + ni], 0, 0, 0);
    __builtin_amdgcn_s_setprio(0);
    asm volatile("s_barrier" ::: "memory");

    // ================= P4: quadrant (1,0); no reads (bA from P3, bB0 from P1) =================
    if (t + 2 < GNT) stageA2(t + 2, 1);
    asm volatile("s_barrier" ::: "memory");
    __builtin_amdgcn_s_setprio(1);
#pragma unroll
    for (int mi = 0; mi < 4; ++mi)
#pragma unroll
      for (int ni = 0; ni < 2; ++ni)
#pragma unroll
        for (int kk = 0; kk < 2; ++kk)
          acc[4 + mi][ni] = __builtin_amdgcn_mfma_f32_16x16x32_bf16(bA[mi][kk], bB0[ni][kk], acc[4 + mi][ni], 0, 0, 0);
    __builtin_amdgcn_s_setprio(0);
    if (t < GNT - 2)       asm volatile("s_waitcnt vmcnt(10)" ::: "memory");
    else if (t == GNT - 2) asm volatile("s_waitcnt vmcnt(4)" ::: "memory");
    asm volatile("s_barrier" ::: "memory");
  }

  // ---- epilogue: bias + f32 store ----
#pragma unroll
  for (int mf = 0; mf < 8; ++mf) {
    int row = m0 + wm * 128 + mf * 16 + g * 4;
#pragma unroll
    for (int n = 0; n < 4; ++n) {
      int col = n0 + wn * 64 + n * 16 + l16;
      float bv = bias[col];
#pragma unroll
      for (int j = 0; j < 4; ++j)
        Cout[(size_t)(row + j) * N + col] = acc[mf][n][j] + bv;
    }
  }
}

// ------------- MFMA flash attention -------------
// qkv: [B*T][3072] f32 (q | k | v, each [h][64]).  y: [B*T][1024] bf16.
__global__ __launch_bounds__(256) void attn_mfma(
    const float* __restrict__ qkv, unsigned short* __restrict__ y) {
  __shared__ char lds[24576];
  char* Kl = lds;
  char* Vl = lds + 8192;
  char* Pl = lds + 16384;

  int bh = blockIdx.y;
  int b = bh >> 4, h = bh & 15;
  int qb = (T_SEQ / 64 - 1) - blockIdx.x;   // big tiles first (tail balance)
  int tid = threadIdx.x;
  int lane = tid & 63, w = tid >> 6;
  int l16 = lane & 15, g = lane >> 4;
  size_t bT = (size_t)b * T_SEQ;
  const float scale = 0.03125f;  // 1024^-0.5

  bf16x8 qf[2];
  {
    const float* qrow = qkv + (bT + qb * 64 + w * 16 + l16) * 3072 + h * 64;
#pragma unroll
    for (int kk = 0; kk < 2; ++kk) {
      f32x4 a = *(const f32x4*)(qrow + kk * 32 + g * 8);
      f32x4 c = *(const f32x4*)(qrow + kk * 32 + g * 8 + 4);
      us8 o;
      o[0] = f2bf(a[0]); o[1] = f2bf(a[1]); o[2] = f2bf(a[2]); o[3] = f2bf(a[3]);
      o[4] = f2bf(c[0]); o[5] = f2bf(c[1]); o[6] = f2bf(c[2]); o[7] = f2bf(c[3]);
      qf[kk] = *(bf16x8*)&o;
    }
  }

  f32x4 yacc[4] = {};
  float mrun[4], lrun[4];
#pragma unroll
  for (int j = 0; j < 4; ++j) { mrun[j] = -3.0e38f; lrun[j] = 0.f; }

  int srow = tid >> 2;
  int c0 = (tid & 3) * 16;

  for (int kb = 0; kb <= qb; ++kb) {
    {
      const float* kp = qkv + (bT + kb * 64 + srow) * 3072 + 1024 + h * 64 + c0;
      f32x4 k0 = *(const f32x4*)(kp + 0);
      f32x4 k1 = *(const f32x4*)(kp + 4);
      f32x4 k2 = *(const f32x4*)(kp + 8);
      f32x4 k3 = *(const f32x4*)(kp + 12);
      us8 pa, pb;
      pa[0]=f2bf(k0[0]); pa[1]=f2bf(k0[1]); pa[2]=f2bf(k0[2]); pa[3]=f2bf(k0[3]);
      pa[4]=f2bf(k1[0]); pa[5]=f2bf(k1[1]); pa[6]=f2bf(k1[2]); pa[7]=f2bf(k1[3]);
      pb[0]=f2bf(k2[0]); pb[1]=f2bf(k2[1]); pb[2]=f2bf(k2[2]); pb[3]=f2bf(k2[3]);
      pb[4]=f2bf(k3[0]); pb[5]=f2bf(k3[1]); pb[6]=f2bf(k3[2]); pb[7]=f2bf(k3[3]);
      *(us8*)(Kl + ((srow * 128 + c0 * 2)      ^ ((srow & 7) << 4))) = pa;
      *(us8*)(Kl + ((srow * 128 + c0 * 2 + 16) ^ ((srow & 7) << 4))) = pb;
      const float* vp = kp + 1024;
      f32x4 v0 = *(const f32x4*)(vp + 0);
      f32x4 v1 = *(const f32x4*)(vp + 4);
      f32x4 v2 = *(const f32x4*)(vp + 8);
      f32x4 v3 = *(const f32x4*)(vp + 12);
      float vals[16] = {v0[0],v0[1],v0[2],v0[3], v1[0],v1[1],v1[2],v1[3],
                        v2[0],v2[1],v2[2],v2[3], v3[0],v3[1],v3[2],v3[3]};
#pragma unroll
      for (int i = 0; i < 16; ++i) {
        int ch = c0 + i;
        *(unsigned short*)(Vl + ((ch * 128 + srow * 2) ^ ((ch & 7) << 4))) = f2bf(vals[i]);
      }
    }
    __syncthreads();

    f32x4 s[4] = {};
#pragma unroll
    for (int kk = 0; kk < 2; ++kk)
#pragma unroll
      for (int n = 0; n < 4; ++n) {
        int krow = n * 16 + l16;
        bf16x8 fb = *(const bf16x8*)(Kl + ((krow * 128 + (kk * 32 + g * 8) * 2) ^ ((krow & 7) << 4)));
        s[n] = __builtin_amdgcn_mfma_f32_16x16x32_bf16(qf[kk], fb, s[n], 0, 0, 0);
      }

    bool diag = (kb == qb);
    float pr[4][4];
    float corr[4];
#pragma unroll
    for (int j = 0; j < 4; ++j) {
      int rloc = w * 16 + g * 4 + j;
      float m = -3.0e38f;
#pragma unroll
      for (int n = 0; n < 4; ++n) {
        float v = s[n][j] * scale;
        if (diag && (n * 16 + l16) > rloc) v = -3.0e38f;
        pr[n][j] = v;
        m = fmaxf(m, v);
      }
      m = fmaxf(m, __shfl_xor(m, 1));
      m = fmaxf(m, __shfl_xor(m, 2));
      m = fmaxf(m, __shfl_xor(m, 4));
      m = fmaxf(m, __shfl_xor(m, 8));
      float mn = fmaxf(mrun[j], m);
      corr[j] = __expf(mrun[j] - mn);
      mrun[j] = mn;
      float ps = 0.f;
#pragma unroll
      for (int n = 0; n < 4; ++n) {
        float e = __expf(pr[n][j] - mn);
        pr[n][j] = e;
        ps += e;
      }
      ps += __shfl_xor(ps, 1);
      ps += __shfl_xor(ps, 2);
      ps += __shfl_xor(ps, 4);
      ps += __shfl_xor(ps, 8);
      lrun[j] = lrun[j] * corr[j] + ps;
    }
#pragma unroll
    for (int n = 0; n < 4; ++n)
#pragma unroll
      for (int j = 0; j < 4; ++j)
        yacc[n][j] *= corr[j];

#pragma unroll
    for (int j = 0; j < 4; ++j) {
      int row = w * 16 + g * 4 + j;
#pragma unroll
      for (int n = 0; n < 4; ++n)
        *(unsigned short*)(Pl + ((row * 128 + (n * 16 + l16) * 2) ^ ((row & 7) << 4))) = f2bf(pr[n][j]);
    }

#pragma unroll
    for (int kk = 0; kk < 2; ++kk) {
      int prow = w * 16 + l16;
      bf16x8 fa = *(const bf16x8*)(Pl + ((prow * 128 + (kk * 32 + g * 8) * 2) ^ ((prow & 7) << 4)));
#pragma unroll
      for (int n = 0; n < 4; ++n) {
        int vrow = n * 16 + l16;
        bf16x8 fb = *(const bf16x8*)(Vl + ((vrow * 128 + (kk * 32 + g * 8) * 2) ^ ((vrow & 7) << 4)));
        yacc[n] = __builtin_amdgcn_mfma_f32_16x16x32_bf16(fa, fb, yacc[n], 0, 0, 0);
      }
    }
    __syncthreads();
  }

#pragma unroll
  for (int j = 0; j < 4; ++j) {
    float inv = 1.0f / lrun[j];
    int row = qb * 64 + w * 16 + g * 4 + j;
    unsigned short* yo = y + (bT + row) * C_DIM + h * 64;
#pragma unroll
    for (int n = 0; n < 4; ++n)
      yo[n * 16 + l16] = f2bf(yacc[n][j] * inv);
  }
}

extern "C" void kernel_launch(void* const* d_in, const int* in_sizes, int n_in,
                              void* d_out, int out_size, void* d_ws, size_t ws_size,
                              hipStream_t stream) {
  const int*   x    = (const int*)d_in[0];
  const float* tok  = (const float*)d_in[1];
  const float* pos  = (const float*)d_in[2];
  const float* wq   = (const float*)d_in[3];
  const float* bq   = (const float*)d_in[4];
  const float* wk   = (const float*)d_in[5];
  const float* bk   = (const float*)d_in[6];
  const float* wv   = (const float*)d_in[7];
  const float* bv   = (const float*)d_in[8];
  const float* wh   = (const float*)d_in[9];
  const float* bhd  = (const float*)d_in[10];
  float* out = (float*)d_out;

  char* ws = (char*)d_ws;
  size_t off = 0;
  auto alloc = [&](size_t bytes) {
    void* p = ws + off;
    off += (bytes + 255) & ~(size_t)255;
    return p;
  };
  unsigned short* h_bf    = (unsigned short*)alloc((size_t)4096 * 1024 * 2);
  unsigned short* wqkv_t  = (unsigned short*)alloc((size_t)3072 * 1024 * 2);
  float*          qbias   = (float*)alloc((size_t)3072 * 4);
  unsigned short* wh_t    = (unsigned short*)alloc((size_t)V_DIM * 1024 * 2);
  float*          qkv     = (float*)alloc((size_t)4096 * 3072 * 4);
  unsigned short* ybf     = (unsigned short*)alloc((size_t)4096 * 1024 * 2);

  embed_kernel<<<4096, 256, 0, stream>>>(x, tok, pos, h_bf);
  repack_qkv<<<dim3(4096, 3), 256, 0, stream>>>(wq, wk, wv, bq, bk, bv, wqkv_t, qbias);
  repack_whead<<<dim3(V_DIM / 64, 16), 256, 0, stream>>>(wh, wh_t);
  // QKV proj: M=4096, N=3072 -> 16 x 12 = 192 blocks (192 % 8 == 0)
  gemm256<<<192, 512, 0, stream>>>(h_bf, wqkv_t, qbias, qkv, 3072, 16);
  attn_mfma<<<dim3(T_SEQ / 64, 2 * H_N), 256, 0, stream>>>(qkv, ybf);
  // head: M=4096, N=32000 -> 16 x 125 = 2000 blocks (2000 % 8 == 0)
  gemm256<<<2000, 512, 0, stream>>>(ybf, wh_t, bhd, out, V_DIM, 16);
}

// Round 7
// 649.599 us; speedup vs baseline: 1.1281x; 1.1281x over previous
//
#include <hip/hip_runtime.h>

#define T_SEQ 2048
#define C_DIM 1024
#define H_N   16
#define HS_D  64
#define V_DIM 32000

typedef float f32x4 __attribute__((ext_vector_type(4)));
typedef __bf16 bf16x8 __attribute__((ext_vector_type(8)));
typedef unsigned short us4 __attribute__((ext_vector_type(4)));
typedef unsigned short us8 __attribute__((ext_vector_type(8)));

__device__ inline unsigned short f2bf(float f) {
  unsigned int u = __float_as_uint(f);
  u = (u + 0x7FFFu + ((u >> 16) & 1u)) >> 16;
  return (unsigned short)u;
}

// ---------------- embed: h = tok_emb[x] + pos_emb, cast to bf16 ----------------
__global__ __launch_bounds__(256) void embed_kernel(
    const int* __restrict__ x, const float* __restrict__ tok,
    const float* __restrict__ pos, unsigned short* __restrict__ h) {
  int idx = blockIdx.x * 256 + threadIdx.x;   // over (B*T*C)/4
  int bt = idx >> 8;                          // 256 float4 per row
  int c4 = (idx & 255) * 4;
  int t = bt & (T_SEQ - 1);
  int tokid = x[bt];
  f32x4 a = *(const f32x4*)(tok + (size_t)tokid * C_DIM + c4);
  f32x4 b = *(const f32x4*)(pos + (size_t)t * C_DIM + c4);
  f32x4 s = a + b;
  us4 o;
  o[0] = f2bf(s[0]); o[1] = f2bf(s[1]); o[2] = f2bf(s[2]); o[3] = f2bf(s[3]);
  *(us4*)(h + (size_t)bt * C_DIM + c4) = o;
}

// ------------- repack wq/wk/wv [H,C,HS] f32 -> bf16 [3072][1024] (N,K) -------------
__global__ __launch_bounds__(256) void repack_qkv(
    const float* __restrict__ wq, const float* __restrict__ wk, const float* __restrict__ wv,
    const float* __restrict__ bq, const float* __restrict__ bk, const float* __restrict__ bv,
    unsigned short* __restrict__ wt, float* __restrict__ biasp) {
  int which = blockIdx.y;
  const float* w = (which == 0) ? wq : (which == 1) ? wk : wv;
  int i = blockIdx.x * 256 + threadIdx.x;   // 0 .. H*C*HS (=1M)
  int d = i & 63;
  int c = (i >> 6) & (C_DIM - 1);
  int hh = i >> 16;
  int n = which * 1024 + hh * 64 + d;
  wt[(size_t)n * C_DIM + c] = f2bf(w[i]);
  if (c == 0) {
    const float* bb = (which == 0) ? bq : (which == 1) ? bk : bv;
    biasp[n] = bb[hh * 64 + d];
  }
}

// ------------- transpose-repack w_head [C,V] f32 -> bf16 [V][C] -------------
__global__ __launch_bounds__(256) void repack_whead(
    const float* __restrict__ wh, unsigned short* __restrict__ wht) {
  __shared__ float tile[64][65];
  int v0 = blockIdx.x * 64;
  int c0 = blockIdx.y * 64;
  int tr = threadIdx.x >> 6;      // 0..3
  int tc = threadIdx.x & 63;
#pragma unroll
  for (int i = 0; i < 16; ++i) {
    int r = i * 4 + tr;
    tile[r][tc] = wh[(size_t)(c0 + r) * V_DIM + v0 + tc];
  }
  __syncthreads();
#pragma unroll
  for (int i = 0; i < 16; ++i) {
    int vr = i * 4 + tr;
    wht[(size_t)(v0 + vr) * C_DIM + c0 + tc] = f2bf(tile[tc][vr]);
  }
}

// ------------- 128x128 4-wave GEMM (m97 structure, known-good) for QKV -------------
__global__ __launch_bounds__(256) void gemm_bf16(
    const unsigned short* __restrict__ A, const unsigned short* __restrict__ Bt,
    const float* __restrict__ bias, float* __restrict__ Cout, int N) {
  const int K = 1024;
  __shared__ unsigned short As[128 * 32];
  __shared__ unsigned short Bs[128 * 32];
  int tid = threadIdx.x;
  int lane = tid & 63, wvi = tid >> 6;
  int m0 = blockIdx.y * 128, n0 = blockIdx.x * 128;
  int wmm = (wvi >> 1) * 64, wnn = (wvi & 1) * 64;
  int r16 = lane & 15, gg = lane >> 4;
  f32x4 acc[4][4] = {};

  for (int k0 = 0; k0 < K; k0 += 32) {
#pragma unroll
    for (int it = 0; it < 2; ++it) {
      int ch = it * 256 + wvi * 64 + lane;
      int row = ch >> 2, cc = (ch & 3) * 8;
      const unsigned short* ga = A + (size_t)(m0 + row) * K + k0 + cc;
      __builtin_amdgcn_global_load_lds(
          (const __attribute__((address_space(1))) void*)ga,
          (__attribute__((address_space(3))) void*)&As[ch * 8], 16, 0, 0);
      const unsigned short* gb = Bt + (size_t)(n0 + row) * K + k0 + cc;
      __builtin_amdgcn_global_load_lds(
          (const __attribute__((address_space(1))) void*)gb,
          (__attribute__((address_space(3))) void*)&Bs[ch * 8], 16, 0, 0);
    }
    __syncthreads();
    bf16x8 fa[4], fb[4];
#pragma unroll
    for (int m = 0; m < 4; ++m)
      fa[m] = *(const bf16x8*)&As[(wmm + m * 16 + r16) * 32 + gg * 8];
#pragma unroll
    for (int n = 0; n < 4; ++n)
      fb[n] = *(const bf16x8*)&Bs[(wnn + n * 16 + r16) * 32 + gg * 8];
#pragma unroll
    for (int m = 0; m < 4; ++m)
#pragma unroll
      for (int n = 0; n < 4; ++n)
        acc[m][n] = __builtin_amdgcn_mfma_f32_16x16x32_bf16(fa[m], fb[n], acc[m][n], 0, 0, 0);
    __syncthreads();
  }
#pragma unroll
  for (int m = 0; m < 4; ++m) {
    int row = m0 + wmm + m * 16 + gg * 4;
#pragma unroll
    for (int n = 0; n < 4; ++n) {
      int col = n0 + wnn + n * 16 + r16;
      float bval = bias[col];
#pragma unroll
      for (int j = 0; j < 4; ++j)
        Cout[(size_t)(row + j) * N + col] = acc[m][n][j] + bval;
    }
  }
}

// ------------- 256x256 double-buffered 2-phase GEMM -------------
// C[M][N] = A[M][1024](bf16) x Bt[N][1024](bf16) + bias[N], f32 out.
// 8 waves (2M x 4N), BK=64. Per K-tile TWO phases (4 barriers, 32 MFMA each):
//   P1: read A-mh0 (8 b128) + ALL B (8 b128, held in regs both phases);
//       stage A-mh1(t+1) [other buf, dead since t-1 P2]; barrier; lgkmcnt(0);
//       32 MFMA (acc mh0 x 4n); vmcnt(8); barrier.
//   P2: read A-mh1 (8 b128); stage A-mh0(t+2)+B(t+2) [regions dead since P1
//       closing barrier; P1's lgkmcnt(0) drained all reads first]; barrier;
//       lgkmcnt(0); 32 MFMA (acc mh1); vmcnt(8); barrier.
// FIFO-counted waits: steady 8/8; tails t=GNT-2: 8/2; t=GNT-1: 0/-.
// Swizzle = R4-verified zero-conflict: 128-B LDS rows, chunk c ^= (row&7),
// pre-swizzled global source + linear gload_lds dest (both-sides rule).
#define GK 1024
#define GNT 16   // K / 64

__global__ __launch_bounds__(512, 1) void gemm256(
    const unsigned short* __restrict__ A, const unsigned short* __restrict__ Bt,
    const float* __restrict__ bias, float* __restrict__ Cout, int N, int Mtiles) {
  __shared__ unsigned short As[2][256 * 64];
  __shared__ unsigned short Bs[2][256 * 64];
  int tid = threadIdx.x;
  int lane = tid & 63;
  int wid = tid >> 6;
  int wm = wid >> 2, wn = wid & 3;
  int l16 = lane & 15, g = lane >> 4;
  int swz = l16 & 7;

  // XCD-bijective swizzle (gridDim.x % 8 == 0); m-tile fastest for B-panel reuse
  int cpx = gridDim.x >> 3;
  int lin = blockIdx.x;
  int wg = (lin & 7) * cpx + (lin >> 3);
  int m0 = (wg % Mtiles) * 256;
  int n0 = (wg / Mtiles) * 256;

  // A half-region mh of K-tile kt: rows {mh*64+(0..63)} u {128+mh*64+(0..63)}; 2 loads
  auto stageA2 = [&](int kt, int mh) {
    unsigned short* lds = As[kt & 1];
#pragma unroll
    for (int q = 0; q < 2; ++q) {
      int chunk = q * 512 + tid;
      int rr = chunk >> 3;
      int row = (rr & 63) + ((rr >> 6) << 7) + mh * 64;
      int cpos = chunk & 7;
      int c = cpos ^ (row & 7);
      const unsigned short* src = A + (size_t)(m0 + row) * GK + kt * 64 + c * 8;
      __builtin_amdgcn_global_load_lds(
          (const __attribute__((address_space(1))) void*)src,
          (__attribute__((address_space(3))) void*)(lds + row * 64 + cpos * 8), 16, 0, 0);
    }
  };
  // full B K-tile: 4 loads
  auto stageB4 = [&](int kt) {
    unsigned short* lds = Bs[kt & 1];
#pragma unroll
    for (int q = 0; q < 4; ++q) {
      int chunk = q * 512 + tid;
      int row = chunk >> 3;
      int cpos = chunk & 7;
      int c = cpos ^ (row & 7);
      const unsigned short* src = Bt + (size_t)(n0 + row) * GK + kt * 64 + c * 8;
      __builtin_amdgcn_global_load_lds(
          (const __attribute__((address_space(1))) void*)src,
          (__attribute__((address_space(3))) void*)(lds + row * 64 + cpos * 8), 16, 0, 0);
    }
  };

  // prologue (14 loads, steady-state FIFO order):
  //   Amh0(0), B(0) | Amh1(0) | Amh0(1), B(1)
  stageA2(0, 0); stageB4(0);
  stageA2(0, 1);
  stageA2(1, 0); stageB4(1);
  asm volatile("s_waitcnt vmcnt(8)" ::: "memory");   // Amh0(0)+B(0) landed
  asm volatile("s_barrier" ::: "memory");

  f32x4 acc[8][4] = {};

  for (int t = 0; t < GNT; ++t) {
    const char* Ab = (const char*)As[t & 1];
    const char* Bb = (const char*)Bs[t & 1];
    bf16x8 bA[4][2], bB[4][2];

    // ================= P1: acc[mh0]; reads A-mh0 + all B =================
#pragma unroll
    for (int mi = 0; mi < 4; ++mi) {
      int row = wm * 128 + mi * 16 + l16;
#pragma unroll
      for (int kk = 0; kk < 2; ++kk)
        bA[mi][kk] = *(const bf16x8*)(Ab + row * 128 + (((kk * 4 + g) ^ swz) * 16));
    }
#pragma unroll
    for (int ni = 0; ni < 4; ++ni) {
      int row = wn * 64 + ni * 16 + l16;
#pragma unroll
      for (int kk = 0; kk < 2; ++kk)
        bB[ni][kk] = *(const bf16x8*)(Bb + row * 128 + (((kk * 4 + g) ^ swz) * 16));
    }
    if (t + 1 < GNT) stageA2(t + 1, 1);
    asm volatile("s_barrier" ::: "memory");
    asm volatile("s_waitcnt lgkmcnt(0)" ::: "memory");
    __builtin_amdgcn_sched_barrier(0);
    __builtin_amdgcn_s_setprio(1);
#pragma unroll
    for (int mi = 0; mi < 4; ++mi)
#pragma unroll
      for (int ni = 0; ni < 4; ++ni)
#pragma unroll
        for (int kk = 0; kk < 2; ++kk)
          acc[mi][ni] = __builtin_amdgcn_mfma_f32_16x16x32_bf16(bA[mi][kk], bB[ni][kk], acc[mi][ni], 0, 0, 0);
    __builtin_amdgcn_s_setprio(0);
    if (t + 1 < GNT) asm volatile("s_waitcnt vmcnt(8)" ::: "memory");
    else             asm volatile("s_waitcnt vmcnt(0)" ::: "memory");
    asm volatile("s_barrier" ::: "memory");

    // ================= P2: acc[mh1]; reads A-mh1 (B held in regs) =================
#pragma unroll
    for (int mi = 0; mi < 4; ++mi) {
      int row = wm * 128 + 64 + mi * 16 + l16;
#pragma unroll
      for (int kk = 0; kk < 2; ++kk)
        bA[mi][kk] = *(const bf16x8*)(Ab + row * 128 + (((kk * 4 + g) ^ swz) * 16));
    }
    if (t + 2 < GNT) { stageA2(t + 2, 0); stageB4(t + 2); }
    asm volatile("s_barrier" ::: "memory");
    asm volatile("s_waitcnt lgkmcnt(0)" ::: "memory");
    __builtin_amdgcn_sched_barrier(0);
    __builtin_amdgcn_s_setprio(1);
#pragma unroll
    for (int mi = 0; mi < 4; ++mi)
#pragma unroll
      for (int ni = 0; ni < 4; ++ni)
#pragma unroll
        for (int kk = 0; kk < 2; ++kk)
          acc[4 + mi][ni] = __builtin_amdgcn_mfma_f32_16x16x32_bf16(bA[mi][kk], bB[ni][kk], acc[4 + mi][ni], 0, 0, 0);
    __builtin_amdgcn_s_setprio(0);
    if (t + 2 < GNT)      asm volatile("s_waitcnt vmcnt(8)" ::: "memory");
    else if (t + 2 == GNT) asm volatile("s_waitcnt vmcnt(2)" ::: "memory");
    asm volatile("s_barrier" ::: "memory");
  }

  // ---- epilogue: bias + f32 store ----
#pragma unroll
  for (int mf = 0; mf < 8; ++mf) {
    int row = m0 + wm * 128 + mf * 16 + g * 4;
#pragma unroll
    for (int n = 0; n < 4; ++n) {
      int col = n0 + wn * 64 + n * 16 + l16;
      float bv = bias[col];
#pragma unroll
      for (int j = 0; j < 4; ++j)
        Cout[(size_t)(row + j) * N + col] = acc[mf][n][j] + bv;
    }
  }
}

// ------------- MFMA flash attention -------------
// qkv: [B*T][3072] f32 (q | k | v, each [h][64]).  y: [B*T][1024] bf16.
__global__ __launch_bounds__(256) void attn_mfma(
    const float* __restrict__ qkv, unsigned short* __restrict__ y) {
  __shared__ char lds[24576];
  char* Kl = lds;
  char* Vl = lds + 8192;
  char* Pl = lds + 16384;

  int bh = blockIdx.y;
  int b = bh >> 4, h = bh & 15;
  int qb = (T_SEQ / 64 - 1) - blockIdx.x;   // big tiles first (tail balance)
  int tid = threadIdx.x;
  int lane = tid & 63, w = tid >> 6;
  int l16 = lane & 15, g = lane >> 4;
  size_t bT = (size_t)b * T_SEQ;
  const float scale = 0.03125f;  // 1024^-0.5

  bf16x8 qf[2];
  {
    const float* qrow = qkv + (bT + qb * 64 + w * 16 + l16) * 3072 + h * 64;
#pragma unroll
    for (int kk = 0; kk < 2; ++kk) {
      f32x4 a = *(const f32x4*)(qrow + kk * 32 + g * 8);
      f32x4 c = *(const f32x4*)(qrow + kk * 32 + g * 8 + 4);
      us8 o;
      o[0] = f2bf(a[0]); o[1] = f2bf(a[1]); o[2] = f2bf(a[2]); o[3] = f2bf(a[3]);
      o[4] = f2bf(c[0]); o[5] = f2bf(c[1]); o[6] = f2bf(c[2]); o[7] = f2bf(c[3]);
      qf[kk] = *(bf16x8*)&o;
    }
  }

  f32x4 yacc[4] = {};
  float mrun[4], lrun[4];
#pragma unroll
  for (int j = 0; j < 4; ++j) { mrun[j] = -3.0e38f; lrun[j] = 0.f; }

  int srow = tid >> 2;
  int c0 = (tid & 3) * 16;

  for (int kb = 0; kb <= qb; ++kb) {
    {
      const float* kp = qkv + (bT + kb * 64 + srow) * 3072 + 1024 + h * 64 + c0;
      f32x4 k0 = *(const f32x4*)(kp + 0);
      f32x4 k1 = *(const f32x4*)(kp + 4);
      f32x4 k2 = *(const f32x4*)(kp + 8);
      f32x4 k3 = *(const f32x4*)(kp + 12);
      us8 pa, pb;
      pa[0]=f2bf(k0[0]); pa[1]=f2bf(k0[1]); pa[2]=f2bf(k0[2]); pa[3]=f2bf(k0[3]);
      pa[4]=f2bf(k1[0]); pa[5]=f2bf(k1[1]); pa[6]=f2bf(k1[2]); pa[7]=f2bf(k1[3]);
      pb[0]=f2bf(k2[0]); pb[1]=f2bf(k2[1]); pb[2]=f2bf(k2[2]); pb[3]=f2bf(k2[3]);
      pb[4]=f2bf(k3[0]); pb[5]=f2bf(k3[1]); pb[6]=f2bf(k3[2]); pb[7]=f2bf(k3[3]);
      *(us8*)(Kl + ((srow * 128 + c0 * 2)      ^ ((srow & 7) << 4))) = pa;
      *(us8*)(Kl + ((srow * 128 + c0 * 2 + 16) ^ ((srow & 7) << 4))) = pb;
      const float* vp = kp + 1024;
      f32x4 v0 = *(const f32x4*)(vp + 0);
      f32x4 v1 = *(const f32x4*)(vp + 4);
      f32x4 v2 = *(const f32x4*)(vp + 8);
      f32x4 v3 = *(const f32x4*)(vp + 12);
      float vals[16] = {v0[0],v0[1],v0[2],v0[3], v1[0],v1[1],v1[2],v1[3],
                        v2[0],v2[1],v2[2],v2[3], v3[0],v3[1],v3[2],v3[3]};
#pragma unroll
      for (int i = 0; i < 16; ++i) {
        int ch = c0 + i;
        *(unsigned short*)(Vl + ((ch * 128 + srow * 2) ^ ((ch & 7) << 4))) = f2bf(vals[i]);
      }
    }
    __syncthreads();

    f32x4 s[4] = {};
#pragma unroll
    for (int kk = 0; kk < 2; ++kk)
#pragma unroll
      for (int n = 0; n < 4; ++n) {
        int krow = n * 16 + l16;
        bf16x8 fb = *(const bf16x8*)(Kl + ((krow * 128 + (kk * 32 + g * 8) * 2) ^ ((krow & 7) << 4)));
        s[n] = __builtin_amdgcn_mfma_f32_16x16x32_bf16(qf[kk], fb, s[n], 0, 0, 0);
      }

    bool diag = (kb == qb);
    float pr[4][4];
    float corr[4];
#pragma unroll
    for (int j = 0; j < 4; ++j) {
      int rloc = w * 16 + g * 4 + j;
      float m = -3.0e38f;
#pragma unroll
      for (int n = 0; n < 4; ++n) {
        float v = s[n][j] * scale;
        if (diag && (n * 16 + l16) > rloc) v = -3.0e38f;
        pr[n][j] = v;
        m = fmaxf(m, v);
      }
      m = fmaxf(m, __shfl_xor(m, 1));
      m = fmaxf(m, __shfl_xor(m, 2));
      m = fmaxf(m, __shfl_xor(m, 4));
      m = fmaxf(m, __shfl_xor(m, 8));
      float mn = fmaxf(mrun[j], m);
      corr[j] = __expf(mrun[j] - mn);
      mrun[j] = mn;
      float ps = 0.f;
#pragma unroll
      for (int n = 0; n < 4; ++n) {
        float e = __expf(pr[n][j] - mn);
        pr[n][j] = e;
        ps += e;
      }
      ps += __shfl_xor(ps, 1);
      ps += __shfl_xor(ps, 2);
      ps += __shfl_xor(ps, 4);
      ps += __shfl_xor(ps, 8);
      lrun[j] = lrun[j] * corr[j] + ps;
    }
#pragma unroll
    for (int n = 0; n < 4; ++n)
#pragma unroll
      for (int j = 0; j < 4; ++j)
        yacc[n][j] *= corr[j];

#pragma unroll
    for (int j = 0; j < 4; ++j) {
      int row = w * 16 + g * 4 + j;
#pragma unroll
      for (int n = 0; n < 4; ++n)
        *(unsigned short*)(Pl + ((row * 128 + (n * 16 + l16) * 2) ^ ((row & 7) << 4))) = f2bf(pr[n][j]);
    }

#pragma unroll
    for (int kk = 0; kk < 2; ++kk) {
      int prow = w * 16 + l16;
      bf16x8 fa = *(const bf16x8*)(Pl + ((prow * 128 + (kk * 32 + g * 8) * 2) ^ ((prow & 7) << 4)));
#pragma unroll
      for (int n = 0; n < 4; ++n) {
        int vrow = n * 16 + l16;
        bf16x8 fb = *(const bf16x8*)(Vl + ((vrow * 128 + (kk * 32 + g * 8) * 2) ^ ((vrow & 7) << 4)));
        yacc[n] = __builtin_amdgcn_mfma_f32_16x16x32_bf16(fa, fb, yacc[n], 0, 0, 0);
      }
    }
    __syncthreads();
  }

#pragma unroll
  for (int j = 0; j < 4; ++j) {
    float inv = 1.0f / lrun[j];
    int row = qb * 64 + w * 16 + g * 4 + j;
    unsigned short* yo = y + (bT + row) * C_DIM + h * 64;
#pragma unroll
    for (int n = 0; n < 4; ++n)
      yo[n * 16 + l16] = f2bf(yacc[n][j] * inv);
  }
}

extern "C" void kernel_launch(void* const* d_in, const int* in_sizes, int n_in,
                              void* d_out, int out_size, void* d_ws, size_t ws_size,
                              hipStream_t stream) {
  const int*   x    = (const int*)d_in[0];
  const float* tok  = (const float*)d_in[1];
  const float* pos  = (const float*)d_in[2];
  const float* wq   = (const float*)d_in[3];
  const float* bq   = (const float*)d_in[4];
  const float* wk   = (const float*)d_in[5];
  const float* bk   = (const float*)d_in[6];
  const float* wv   = (const float*)d_in[7];
  const float* bv   = (const float*)d_in[8];
  const float* wh   = (const float*)d_in[9];
  const float* bhd  = (const float*)d_in[10];
  float* out = (float*)d_out;

  char* ws = (char*)d_ws;
  size_t off = 0;
  auto alloc = [&](size_t bytes) {
    void* p = ws + off;
    off += (bytes + 255) & ~(size_t)255;
    return p;
  };
  unsigned short* h_bf    = (unsigned short*)alloc((size_t)4096 * 1024 * 2);
  unsigned short* wqkv_t  = (unsigned short*)alloc((size_t)3072 * 1024 * 2);
  float*          qbias   = (float*)alloc((size_t)3072 * 4);
  unsigned short* wh_t    = (unsigned short*)alloc((size_t)V_DIM * 1024 * 2);
  float*          qkv     = (float*)alloc((size_t)4096 * 3072 * 4);
  unsigned short* ybf     = (unsigned short*)alloc((size_t)4096 * 1024 * 2);

  embed_kernel<<<4096, 256, 0, stream>>>(x, tok, pos, h_bf);
  repack_qkv<<<dim3(4096, 3), 256, 0, stream>>>(wq, wk, wv, bq, bk, bv, wqkv_t, qbias);
  repack_whead<<<dim3(V_DIM / 64, 16), 256, 0, stream>>>(wh, wh_t);
  // QKV proj: 128^2 tiles -> 24 x 32 = 768 blocks (~3 blocks/CU)
  gemm_bf16<<<dim3(3072 / 128, 4096 / 128), 256, 0, stream>>>(h_bf, wqkv_t, qbias, qkv, 3072);
  attn_mfma<<<dim3(T_SEQ / 64, 2 * H_N), 256, 0, stream>>>(qkv, ybf);
  // head: M=4096, N=32000 -> 16 x 125 = 2000 blocks (2000 % 8 == 0)
  gemm256<<<2000, 512, 0, stream>>>(ybf, wh_t, bhd, out, V_DIM, 16);
}

// Round 8
// 587.154 us; speedup vs baseline: 1.2481x; 1.1064x over previous
//
#include <hip/hip_runtime.h>

#define T_SEQ 2048
#define C_DIM 1024
#define H_N   16
#define HS_D  64
#define V_DIM 32000

typedef float f32x4 __attribute__((ext_vector_type(4)));
typedef __bf16 bf16x8 __attribute__((ext_vector_type(8)));
typedef unsigned short us4 __attribute__((ext_vector_type(4)));
typedef unsigned short us8 __attribute__((ext_vector_type(8)));

__device__ inline unsigned short f2bf(float f) {
  unsigned int u = __float_as_uint(f);
  u = (u + 0x7FFFu + ((u >> 16) & 1u)) >> 16;
  return (unsigned short)u;
}

// ---------------- embed: h = tok_emb[x] + pos_emb, cast to bf16 ----------------
__global__ __launch_bounds__(256) void embed_kernel(
    const int* __restrict__ x, const float* __restrict__ tok,
    const float* __restrict__ pos, unsigned short* __restrict__ h) {
  int idx = blockIdx.x * 256 + threadIdx.x;   // over (B*T*C)/4
  int bt = idx >> 8;                          // 256 float4 per row
  int c4 = (idx & 255) * 4;
  int t = bt & (T_SEQ - 1);
  int tokid = x[bt];
  f32x4 a = *(const f32x4*)(tok + (size_t)tokid * C_DIM + c4);
  f32x4 b = *(const f32x4*)(pos + (size_t)t * C_DIM + c4);
  f32x4 s = a + b;
  us4 o;
  o[0] = f2bf(s[0]); o[1] = f2bf(s[1]); o[2] = f2bf(s[2]); o[3] = f2bf(s[3]);
  *(us4*)(h + (size_t)bt * C_DIM + c4) = o;
}

// ------------- repack wq/wk/wv [H,C,HS] f32 -> bf16 [3072][1024] (N,K) -------------
__global__ __launch_bounds__(256) void repack_qkv(
    const float* __restrict__ wq, const float* __restrict__ wk, const float* __restrict__ wv,
    const float* __restrict__ bq, const float* __restrict__ bk, const float* __restrict__ bv,
    unsigned short* __restrict__ wt, float* __restrict__ biasp) {
  int which = blockIdx.y;
  const float* w = (which == 0) ? wq : (which == 1) ? wk : wv;
  int i = blockIdx.x * 256 + threadIdx.x;   // 0 .. H*C*HS (=1M)
  int d = i & 63;
  int c = (i >> 6) & (C_DIM - 1);
  int hh = i >> 16;
  int n = which * 1024 + hh * 64 + d;
  wt[(size_t)n * C_DIM + c] = f2bf(w[i]);
  if (c == 0) {
    const float* bb = (which == 0) ? bq : (which == 1) ? bk : bv;
    biasp[n] = bb[hh * 64 + d];
  }
}

// ------------- transpose-repack w_head [C,V] f32 -> bf16 [V][C] -------------
__global__ __launch_bounds__(256) void repack_whead(
    const float* __restrict__ wh, unsigned short* __restrict__ wht) {
  __shared__ float tile[64][65];
  int v0 = blockIdx.x * 64;
  int c0 = blockIdx.y * 64;
  int tr = threadIdx.x >> 6;      // 0..3
  int tc = threadIdx.x & 63;
#pragma unroll
  for (int i = 0; i < 16; ++i) {
    int r = i * 4 + tr;
    tile[r][tc] = wh[(size_t)(c0 + r) * V_DIM + v0 + tc];
  }
  __syncthreads();
#pragma unroll
  for (int i = 0; i < 16; ++i) {
    int vr = i * 4 + tr;
    wht[(size_t)(v0 + vr) * C_DIM + c0 + tc] = f2bf(tile[tc][vr]);
  }
}

// ------------- 128x128 4-wave GEMM (m97 structure), bf16 OUTPUT (for QKV) -------------
__global__ __launch_bounds__(256) void gemm_bf16_o16(
    const unsigned short* __restrict__ A, const unsigned short* __restrict__ Bt,
    const float* __restrict__ bias, unsigned short* __restrict__ Cout, int N) {
  const int K = 1024;
  __shared__ unsigned short As[128 * 32];
  __shared__ unsigned short Bs[128 * 32];
  int tid = threadIdx.x;
  int lane = tid & 63, wvi = tid >> 6;
  int m0 = blockIdx.y * 128, n0 = blockIdx.x * 128;
  int wmm = (wvi >> 1) * 64, wnn = (wvi & 1) * 64;
  int r16 = lane & 15, gg = lane >> 4;
  f32x4 acc[4][4] = {};

  for (int k0 = 0; k0 < K; k0 += 32) {
#pragma unroll
    for (int it = 0; it < 2; ++it) {
      int ch = it * 256 + wvi * 64 + lane;
      int row = ch >> 2, cc = (ch & 3) * 8;
      const unsigned short* ga = A + (size_t)(m0 + row) * K + k0 + cc;
      __builtin_amdgcn_global_load_lds(
          (const __attribute__((address_space(1))) void*)ga,
          (__attribute__((address_space(3))) void*)&As[ch * 8], 16, 0, 0);
      const unsigned short* gb = Bt + (size_t)(n0 + row) * K + k0 + cc;
      __builtin_amdgcn_global_load_lds(
          (const __attribute__((address_space(1))) void*)gb,
          (__attribute__((address_space(3))) void*)&Bs[ch * 8], 16, 0, 0);
    }
    __syncthreads();
    bf16x8 fa[4], fb[4];
#pragma unroll
    for (int m = 0; m < 4; ++m)
      fa[m] = *(const bf16x8*)&As[(wmm + m * 16 + r16) * 32 + gg * 8];
#pragma unroll
    for (int n = 0; n < 4; ++n)
      fb[n] = *(const bf16x8*)&Bs[(wnn + n * 16 + r16) * 32 + gg * 8];
#pragma unroll
    for (int m = 0; m < 4; ++m)
#pragma unroll
      for (int n = 0; n < 4; ++n)
        acc[m][n] = __builtin_amdgcn_mfma_f32_16x16x32_bf16(fa[m], fb[n], acc[m][n], 0, 0, 0);
    __syncthreads();
  }
#pragma unroll
  for (int m = 0; m < 4; ++m) {
    int row = m0 + wmm + m * 16 + gg * 4;
#pragma unroll
    for (int n = 0; n < 4; ++n) {
      int col = n0 + wnn + n * 16 + r16;
      float bval = bias[col];
#pragma unroll
      for (int j = 0; j < 4; ++j)
        Cout[(size_t)(row + j) * N + col] = f2bf(acc[m][n][j] + bval);
    }
  }
}

// ------------- transpose V: qkv_bf [B*T][3072] (cols 2048..3071) -> vt [B*H][64][T] -------------
__global__ __launch_bounds__(256) void transpose_v(
    const unsigned short* __restrict__ qkv, unsigned short* __restrict__ vt) {
  __shared__ unsigned short tile[64][72];
  int bh = blockIdx.y;
  int b = bh >> 4, h = bh & 15;
  int tb = blockIdx.x;
  int r = threadIdx.x >> 2;          // 0..63
  int c0 = (threadIdx.x & 3) * 16;
  const unsigned short* src = qkv + ((size_t)(b * T_SEQ) + tb * 64 + r) * 3072 + 2048 + h * 64 + c0;
  *(us8*)&tile[r][c0] = *(const us8*)src;
  *(us8*)&tile[r][c0 + 8] = *(const us8*)(src + 8);
  __syncthreads();
  unsigned short* dst = vt + (size_t)bh * 64 * T_SEQ + (size_t)r * T_SEQ + tb * 64 + c0;
  us8 o1, o2;
#pragma unroll
  for (int i = 0; i < 8; ++i) { o1[i] = tile[c0 + i][r]; o2[i] = tile[c0 + 8 + i][r]; }
  *(us8*)dst = o1;
  *(us8*)(dst + 8) = o2;
}

// ------------- 256x256 double-buffered 2-phase GEMM (R7, best head structure) -------------
#define GK 1024
#define GNT 16   // K / 64

__global__ __launch_bounds__(512, 1) void gemm256(
    const unsigned short* __restrict__ A, const unsigned short* __restrict__ Bt,
    const float* __restrict__ bias, float* __restrict__ Cout, int N, int Mtiles) {
  __shared__ unsigned short As[2][256 * 64];
  __shared__ unsigned short Bs[2][256 * 64];
  int tid = threadIdx.x;
  int lane = tid & 63;
  int wid = tid >> 6;
  int wm = wid >> 2, wn = wid & 3;
  int l16 = lane & 15, g = lane >> 4;
  int swz = l16 & 7;

  int cpx = gridDim.x >> 3;
  int lin = blockIdx.x;
  int wg = (lin & 7) * cpx + (lin >> 3);
  int m0 = (wg % Mtiles) * 256;
  int n0 = (wg / Mtiles) * 256;

  auto stageA2 = [&](int kt, int mh) {
    unsigned short* lds = As[kt & 1];
#pragma unroll
    for (int q = 0; q < 2; ++q) {
      int chunk = q * 512 + tid;
      int rr = chunk >> 3;
      int row = (rr & 63) + ((rr >> 6) << 7) + mh * 64;
      int cpos = chunk & 7;
      int c = cpos ^ (row & 7);
      const unsigned short* src = A + (size_t)(m0 + row) * GK + kt * 64 + c * 8;
      __builtin_amdgcn_global_load_lds(
          (const __attribute__((address_space(1))) void*)src,
          (__attribute__((address_space(3))) void*)(lds + row * 64 + cpos * 8), 16, 0, 0);
    }
  };
  auto stageB4 = [&](int kt) {
    unsigned short* lds = Bs[kt & 1];
#pragma unroll
    for (int q = 0; q < 4; ++q) {
      int chunk = q * 512 + tid;
      int row = chunk >> 3;
      int cpos = chunk & 7;
      int c = cpos ^ (row & 7);
      const unsigned short* src = Bt + (size_t)(n0 + row) * GK + kt * 64 + c * 8;
      __builtin_amdgcn_global_load_lds(
          (const __attribute__((address_space(1))) void*)src,
          (__attribute__((address_space(3))) void*)(lds + row * 64 + cpos * 8), 16, 0, 0);
    }
  };

  stageA2(0, 0); stageB4(0);
  stageA2(0, 1);
  stageA2(1, 0); stageB4(1);
  asm volatile("s_waitcnt vmcnt(8)" ::: "memory");
  asm volatile("s_barrier" ::: "memory");

  f32x4 acc[8][4] = {};

  for (int t = 0; t < GNT; ++t) {
    const char* Ab = (const char*)As[t & 1];
    const char* Bb = (const char*)Bs[t & 1];
    bf16x8 bA[4][2], bB[4][2];

#pragma unroll
    for (int mi = 0; mi < 4; ++mi) {
      int row = wm * 128 + mi * 16 + l16;
#pragma unroll
      for (int kk = 0; kk < 2; ++kk)
        bA[mi][kk] = *(const bf16x8*)(Ab + row * 128 + (((kk * 4 + g) ^ swz) * 16));
    }
#pragma unroll
    for (int ni = 0; ni < 4; ++ni) {
      int row = wn * 64 + ni * 16 + l16;
#pragma unroll
      for (int kk = 0; kk < 2; ++kk)
        bB[ni][kk] = *(const bf16x8*)(Bb + row * 128 + (((kk * 4 + g) ^ swz) * 16));
    }
    if (t + 1 < GNT) stageA2(t + 1, 1);
    asm volatile("s_barrier" ::: "memory");
    asm volatile("s_waitcnt lgkmcnt(0)" ::: "memory");
    __builtin_amdgcn_sched_barrier(0);
    __builtin_amdgcn_s_setprio(1);
#pragma unroll
    for (int mi = 0; mi < 4; ++mi)
#pragma unroll
      for (int ni = 0; ni < 4; ++ni)
#pragma unroll
        for (int kk = 0; kk < 2; ++kk)
          acc[mi][ni] = __builtin_amdgcn_mfma_f32_16x16x32_bf16(bA[mi][kk], bB[ni][kk], acc[mi][ni], 0, 0, 0);
    __builtin_amdgcn_s_setprio(0);
    if (t + 1 < GNT) asm volatile("s_waitcnt vmcnt(8)" ::: "memory");
    else             asm volatile("s_waitcnt vmcnt(0)" ::: "memory");
    asm volatile("s_barrier" ::: "memory");

#pragma unroll
    for (int mi = 0; mi < 4; ++mi) {
      int row = wm * 128 + 64 + mi * 16 + l16;
#pragma unroll
      for (int kk = 0; kk < 2; ++kk)
        bA[mi][kk] = *(const bf16x8*)(Ab + row * 128 + (((kk * 4 + g) ^ swz) * 16));
    }
    if (t + 2 < GNT) { stageA2(t + 2, 0); stageB4(t + 2); }
    asm volatile("s_barrier" ::: "memory");
    asm volatile("s_waitcnt lgkmcnt(0)" ::: "memory");
    __builtin_amdgcn_sched_barrier(0);
    __builtin_amdgcn_s_setprio(1);
#pragma unroll
    for (int mi = 0; mi < 4; ++mi)
#pragma unroll
      for (int ni = 0; ni < 4; ++ni)
#pragma unroll
        for (int kk = 0; kk < 2; ++kk)
          acc[4 + mi][ni] = __builtin_amdgcn_mfma_f32_16x16x32_bf16(bA[mi][kk], bB[ni][kk], acc[4 + mi][ni], 0, 0, 0);
    __builtin_amdgcn_s_setprio(0);
    if (t + 2 < GNT)       asm volatile("s_waitcnt vmcnt(8)" ::: "memory");
    else if (t + 2 == GNT) asm volatile("s_waitcnt vmcnt(2)" ::: "memory");
    asm volatile("s_barrier" ::: "memory");
  }

#pragma unroll
  for (int mf = 0; mf < 8; ++mf) {
    int row = m0 + wm * 128 + mf * 16 + g * 4;
#pragma unroll
    for (int n = 0; n < 4; ++n) {
      int col = n0 + wn * 64 + n * 16 + l16;
      float bv = bias[col];
#pragma unroll
      for (int j = 0; j < 4; ++j)
        Cout[(size_t)(row + j) * N + col] = acc[mf][n][j] + bv;
    }
  }
}

// ------------- MFMA flash attention, bf16 in, DMA-staged, double-buffered -------------
// qkv: [B*T][3072] bf16 (q|k|v per head); vt: [B*H][64][T] bf16; y: [B*T][1024] bf16.
// Block = 4 waves, one 64-query tile of one (b,h). Per kv-tile: stage next tile
// (4 x global_load_lds), counted vmcnt(4), 2 barriers; QK^T 8 MFMA; in-reg softmax;
// P via LDS strip; PV 8 MFMA. K/Vt LDS layout = GEMM's verified zero-conflict
// swizzle (linear dest chunk, source col c=cpos^(row&7), read (kk*4+g)^(row&7)).
__global__ __launch_bounds__(256) void attn_mfma(
    const unsigned short* __restrict__ qkv, const unsigned short* __restrict__ vt,
    unsigned short* __restrict__ y) {
  __shared__ unsigned short Kl[2][4096];
  __shared__ unsigned short Vl[2][4096];
  __shared__ char Pl[8192];

  int bh = blockIdx.y;
  int b = bh >> 4, h = bh & 15;
  int qb = (T_SEQ / 64 - 1) - blockIdx.x;   // big tiles first
  int tid = threadIdx.x;
  int lane = tid & 63, w = tid >> 6;
  int l16 = lane & 15, g = lane >> 4;
  size_t bT = (size_t)b * T_SEQ;
  const float scale = 0.03125f;  // 1024^-0.5

  // Q fragments (bf16 direct)
  const unsigned short* qrow = qkv + (bT + qb * 64 + w * 16 + l16) * 3072 + h * 64;
  bf16x8 qf[2] = { *(const bf16x8*)(qrow + g * 8), *(const bf16x8*)(qrow + 32 + g * 8) };

  f32x4 yacc[4] = {};
  float mrun[4], lrun[4];
#pragma unroll
  for (int j = 0; j < 4; ++j) { mrun[j] = -3.0e38f; lrun[j] = 0.f; }

  auto stageK = [&](int kb, int buf) {
    const unsigned short* base = qkv + (bT + kb * 64) * 3072 + 1024 + h * 64;
#pragma unroll
    for (int q2 = 0; q2 < 2; ++q2) {
      int chunk = q2 * 256 + tid;
      int row = chunk >> 3, cpos = chunk & 7;
      int c = cpos ^ (row & 7);
      const unsigned short* src = base + (size_t)row * 3072 + c * 8;
      __builtin_amdgcn_global_load_lds(
          (const __attribute__((address_space(1))) void*)src,
          (__attribute__((address_space(3))) void*)&Kl[buf][chunk * 8], 16, 0, 0);
    }
  };
  auto stageV = [&](int kb, int buf) {
    const unsigned short* base = vt + (size_t)bh * 64 * T_SEQ + kb * 64;
#pragma unroll
    for (int q2 = 0; q2 < 2; ++q2) {
      int chunk = q2 * 256 + tid;
      int row = chunk >> 3, cpos = chunk & 7;
      int c = cpos ^ (row & 7);
      const unsigned short* src = base + (size_t)row * T_SEQ + c * 8;
      __builtin_amdgcn_global_load_lds(
          (const __attribute__((address_space(1))) void*)src,
          (__attribute__((address_space(3))) void*)&Vl[buf][chunk * 8], 16, 0, 0);
    }
  };

  stageK(0, 0); stageV(0, 0);

  for (int kb = 0; kb <= qb; ++kb) {
    int buf = kb & 1;
    if (kb < qb) { stageK(kb + 1, buf ^ 1); stageV(kb + 1, buf ^ 1); }
    if (kb < qb) asm volatile("s_waitcnt vmcnt(4)" ::: "memory");
    else         asm volatile("s_waitcnt vmcnt(0)" ::: "memory");
    asm volatile("s_barrier" ::: "memory");

    // ---- S = Q K^T ----
    f32x4 s[4] = {};
#pragma unroll
    for (int kk = 0; kk < 2; ++kk)
#pragma unroll
      for (int n = 0; n < 4; ++n) {
        int krow = n * 16 + l16;
        bf16x8 fb = *(const bf16x8*)((const char*)Kl[buf] + krow * 128 + (((kk * 4 + g) ^ (krow & 7)) * 16));
        s[n] = __builtin_amdgcn_mfma_f32_16x16x32_bf16(qf[kk], fb, s[n], 0, 0, 0);
      }

    // ---- online softmax ----
    bool diag = (kb == qb);
    float pr[4][4];
    float corr[4];
#pragma unroll
    for (int j = 0; j < 4; ++j) {
      int rloc = w * 16 + g * 4 + j;
      float m = -3.0e38f;
#pragma unroll
      for (int n = 0; n < 4; ++n) {
        float v = s[n][j] * scale;
        if (diag && (n * 16 + l16) > rloc) v = -3.0e38f;
        pr[n][j] = v;
        m = fmaxf(m, v);
      }
      m = fmaxf(m, __shfl_xor(m, 1));
      m = fmaxf(m, __shfl_xor(m, 2));
      m = fmaxf(m, __shfl_xor(m, 4));
      m = fmaxf(m, __shfl_xor(m, 8));
      float mn = fmaxf(mrun[j], m);
      corr[j] = __expf(mrun[j] - mn);
      mrun[j] = mn;
      float ps = 0.f;
#pragma unroll
      for (int n = 0; n < 4; ++n) {
        float e = __expf(pr[n][j] - mn);
        pr[n][j] = e;
        ps += e;
      }
      ps += __shfl_xor(ps, 1);
      ps += __shfl_xor(ps, 2);
      ps += __shfl_xor(ps, 4);
      ps += __shfl_xor(ps, 8);
      lrun[j] = lrun[j] * corr[j] + ps;
    }
#pragma unroll
    for (int n = 0; n < 4; ++n)
#pragma unroll
      for (int j = 0; j < 4; ++j)
        yacc[n][j] *= corr[j];

    // ---- P strip (wave-private rows w*16..w*16+15) ----
#pragma unroll
    for (int j = 0; j < 4; ++j) {
      int row = w * 16 + g * 4 + j;
#pragma unroll
      for (int n = 0; n < 4; ++n)
        *(unsigned short*)(Pl + ((row * 128 + (n * 16 + l16) * 2) ^ ((row & 7) << 4))) = f2bf(pr[n][j]);
    }

    // ---- y += P V ----
#pragma unroll
    for (int kk = 0; kk < 2; ++kk) {
      int prow = w * 16 + l16;
      bf16x8 fa = *(const bf16x8*)(Pl + ((prow * 128 + (kk * 32 + g * 8) * 2) ^ ((prow & 7) << 4)));
#pragma unroll
      for (int n = 0; n < 4; ++n) {
        int vrow = n * 16 + l16;
        bf16x8 fbv = *(const bf16x8*)((const char*)Vl[buf] + vrow * 128 + (((kk * 4 + g) ^ (vrow & 7)) * 16));
        yacc[n] = __builtin_amdgcn_mfma_f32_16x16x32_bf16(fa, fbv, yacc[n], 0, 0, 0);
      }
    }
    asm volatile("s_barrier" ::: "memory");   // protect buf before next restage
  }

  // ---- output ----
#pragma unroll
  for (int j = 0; j < 4; ++j) {
    float inv = 1.0f / lrun[j];
    int row = qb * 64 + w * 16 + g * 4 + j;
    unsigned short* yo = y + (bT + row) * C_DIM + h * 64;
#pragma unroll
    for (int n = 0; n < 4; ++n)
      yo[n * 16 + l16] = f2bf(yacc[n][j] * inv);
  }
}

extern "C" void kernel_launch(void* const* d_in, const int* in_sizes, int n_in,
                              void* d_out, int out_size, void* d_ws, size_t ws_size,
                              hipStream_t stream) {
  const int*   x    = (const int*)d_in[0];
  const float* tok  = (const float*)d_in[1];
  const float* pos  = (const float*)d_in[2];
  const float* wq   = (const float*)d_in[3];
  const float* bq   = (const float*)d_in[4];
  const float* wk   = (const float*)d_in[5];
  const float* bk   = (const float*)d_in[6];
  const float* wv   = (const float*)d_in[7];
  const float* bv   = (const float*)d_in[8];
  const float* wh   = (const float*)d_in[9];
  const float* bhd  = (const float*)d_in[10];
  float* out = (float*)d_out;

  char* ws = (char*)d_ws;
  size_t off = 0;
  auto alloc = [&](size_t bytes) {
    void* p = ws + off;
    off += (bytes + 255) & ~(size_t)255;
    return p;
  };
  unsigned short* h_bf    = (unsigned short*)alloc((size_t)4096 * 1024 * 2);
  unsigned short* wqkv_t  = (unsigned short*)alloc((size_t)3072 * 1024 * 2);
  float*          qbias   = (float*)alloc((size_t)3072 * 4);
  unsigned short* wh_t    = (unsigned short*)alloc((size_t)V_DIM * 1024 * 2);
  unsigned short* qkv_bf  = (unsigned short*)alloc((size_t)4096 * 3072 * 2);
  unsigned short* vtb     = (unsigned short*)alloc((size_t)32 * 64 * T_SEQ * 2);
  unsigned short* ybf     = (unsigned short*)alloc((size_t)4096 * 1024 * 2);

  embed_kernel<<<4096, 256, 0, stream>>>(x, tok, pos, h_bf);
  repack_qkv<<<dim3(4096, 3), 256, 0, stream>>>(wq, wk, wv, bq, bk, bv, wqkv_t, qbias);
  repack_whead<<<dim3(V_DIM / 64, 16), 256, 0, stream>>>(wh, wh_t);
  // QKV proj (bf16 out): 24 x 32 = 768 blocks
  gemm_bf16_o16<<<dim3(3072 / 128, 4096 / 128), 256, 0, stream>>>(h_bf, wqkv_t, qbias, qkv_bf, 3072);
  transpose_v<<<dim3(T_SEQ / 64, 2 * H_N), 256, 0, stream>>>(qkv_bf, vtb);
  attn_mfma<<<dim3(T_SEQ / 64, 2 * H_N), 256, 0, stream>>>(qkv_bf, vtb, ybf);
  // head: M=4096, N=32000 -> 2000 blocks
  gemm256<<<2000, 512, 0, stream>>>(ybf, wh_t, bhd, out, V_DIM, 16);
}

// Round 9
// 559.825 us; speedup vs baseline: 1.3091x; 1.0488x over previous
//
#include <hip/hip_runtime.h>

#define T_SEQ 2048
#define C_DIM 1024
#define H_N   16
#define HS_D  64
#define V_DIM 32000

typedef float f32x4 __attribute__((ext_vector_type(4)));
typedef __bf16 bf16x8 __attribute__((ext_vector_type(8)));
typedef unsigned short us4 __attribute__((ext_vector_type(4)));
typedef unsigned short us8 __attribute__((ext_vector_type(8)));

__device__ inline unsigned short f2bf(float f) {
  unsigned int u = __float_as_uint(f);
  u = (u + 0x7FFFu + ((u >> 16) & 1u)) >> 16;
  return (unsigned short)u;
}

// ---------------- embed: h = tok_emb[x] + pos_emb, cast to bf16 ----------------
__global__ __launch_bounds__(256) void embed_kernel(
    const int* __restrict__ x, const float* __restrict__ tok,
    const float* __restrict__ pos, unsigned short* __restrict__ h) {
  int idx = blockIdx.x * 256 + threadIdx.x;   // over (B*T*C)/4
  int bt = idx >> 8;                          // 256 float4 per row
  int c4 = (idx & 255) * 4;
  int t = bt & (T_SEQ - 1);
  int tokid = x[bt];
  f32x4 a = *(const f32x4*)(tok + (size_t)tokid * C_DIM + c4);
  f32x4 b = *(const f32x4*)(pos + (size_t)t * C_DIM + c4);
  f32x4 s = a + b;
  us4 o;
  o[0] = f2bf(s[0]); o[1] = f2bf(s[1]); o[2] = f2bf(s[2]); o[3] = f2bf(s[3]);
  *(us4*)(h + (size_t)bt * C_DIM + c4) = o;
}

// ------------- repack wq/wk/wv [H,C,HS] f32 -> bf16 [3072][1024] (N,K) -------------
__global__ __launch_bounds__(256) void repack_qkv(
    const float* __restrict__ wq, const float* __restrict__ wk, const float* __restrict__ wv,
    const float* __restrict__ bq, const float* __restrict__ bk, const float* __restrict__ bv,
    unsigned short* __restrict__ wt, float* __restrict__ biasp) {
  int which = blockIdx.y;
  const float* w = (which == 0) ? wq : (which == 1) ? wk : wv;
  int i = blockIdx.x * 256 + threadIdx.x;   // 0 .. H*C*HS (=1M)
  int d = i & 63;
  int c = (i >> 6) & (C_DIM - 1);
  int hh = i >> 16;
  int n = which * 1024 + hh * 64 + d;
  wt[(size_t)n * C_DIM + c] = f2bf(w[i]);
  if (c == 0) {
    const float* bb = (which == 0) ? bq : (which == 1) ? bk : bv;
    biasp[n] = bb[hh * 64 + d];
  }
}

// ------------- transpose-repack w_head [C,V] f32 -> bf16 [V][C] -------------
__global__ __launch_bounds__(256) void repack_whead(
    const float* __restrict__ wh, unsigned short* __restrict__ wht) {
  __shared__ float tile[64][65];
  int v0 = blockIdx.x * 64;
  int c0 = blockIdx.y * 64;
  int tr = threadIdx.x >> 6;      // 0..3
  int tc = threadIdx.x & 63;
#pragma unroll
  for (int i = 0; i < 16; ++i) {
    int r = i * 4 + tr;
    tile[r][tc] = wh[(size_t)(c0 + r) * V_DIM + v0 + tc];
  }
  __syncthreads();
#pragma unroll
  for (int i = 0; i < 16; ++i) {
    int vr = i * 4 + tr;
    wht[(size_t)(v0 + vr) * C_DIM + c0 + tc] = f2bf(tile[tc][vr]);
  }
}

// ------------- 128x128 4-wave GEMM (m97 structure) + XCD swizzle, bf16 out (QKV) -------------
// grid: 1D, Mtiles m-fastest within XCD chunk for B-panel L2 residency.
__global__ __launch_bounds__(256) void gemm_bf16_o16(
    const unsigned short* __restrict__ A, const unsigned short* __restrict__ Bt,
    const float* __restrict__ bias, unsigned short* __restrict__ Cout, int N, int Mtiles) {
  const int K = 1024;
  __shared__ unsigned short As[128 * 32];
  __shared__ unsigned short Bs[128 * 32];
  int tid = threadIdx.x;
  int lane = tid & 63, wvi = tid >> 6;
  int cpx = gridDim.x >> 3;
  int lin = blockIdx.x;
  int wg = (lin & 7) * cpx + (lin >> 3);
  int m0 = (wg % Mtiles) * 128;
  int n0 = (wg / Mtiles) * 128;
  int wmm = (wvi >> 1) * 64, wnn = (wvi & 1) * 64;
  int r16 = lane & 15, gg = lane >> 4;
  f32x4 acc[4][4] = {};

  for (int k0 = 0; k0 < K; k0 += 32) {
#pragma unroll
    for (int it = 0; it < 2; ++it) {
      int ch = it * 256 + wvi * 64 + lane;
      int row = ch >> 2, cc = (ch & 3) * 8;
      const unsigned short* ga = A + (size_t)(m0 + row) * K + k0 + cc;
      __builtin_amdgcn_global_load_lds(
          (const __attribute__((address_space(1))) void*)ga,
          (__attribute__((address_space(3))) void*)&As[ch * 8], 16, 0, 0);
      const unsigned short* gb = Bt + (size_t)(n0 + row) * K + k0 + cc;
      __builtin_amdgcn_global_load_lds(
          (const __attribute__((address_space(1))) void*)gb,
          (__attribute__((address_space(3))) void*)&Bs[ch * 8], 16, 0, 0);
    }
    __syncthreads();
    bf16x8 fa[4], fb[4];
#pragma unroll
    for (int m = 0; m < 4; ++m)
      fa[m] = *(const bf16x8*)&As[(wmm + m * 16 + r16) * 32 + gg * 8];
#pragma unroll
    for (int n = 0; n < 4; ++n)
      fb[n] = *(const bf16x8*)&Bs[(wnn + n * 16 + r16) * 32 + gg * 8];
#pragma unroll
    for (int m = 0; m < 4; ++m)
#pragma unroll
      for (int n = 0; n < 4; ++n)
        acc[m][n] = __builtin_amdgcn_mfma_f32_16x16x32_bf16(fa[m], fb[n], acc[m][n], 0, 0, 0);
    __syncthreads();
  }
#pragma unroll
  for (int m = 0; m < 4; ++m) {
    int row = m0 + wmm + m * 16 + gg * 4;
#pragma unroll
    for (int n = 0; n < 4; ++n) {
      int col = n0 + wnn + n * 16 + r16;
      float bval = bias[col];
#pragma unroll
      for (int j = 0; j < 4; ++j)
        Cout[(size_t)(row + j) * N + col] = f2bf(acc[m][n][j] + bval);
    }
  }
}

// ------------- transpose V: qkv_bf [B*T][3072] (cols 2048..3071) -> vt [B*H][64][T] -------------
__global__ __launch_bounds__(256) void transpose_v(
    const unsigned short* __restrict__ qkv, unsigned short* __restrict__ vt) {
  __shared__ unsigned short tile[64][72];
  int bh = blockIdx.y;
  int b = bh >> 4, h = bh & 15;
  int tb = blockIdx.x;
  int r = threadIdx.x >> 2;          // 0..63
  int c0 = (threadIdx.x & 3) * 16;
  const unsigned short* src = qkv + ((size_t)(b * T_SEQ) + tb * 64 + r) * 3072 + 2048 + h * 64 + c0;
  *(us8*)&tile[r][c0] = *(const us8*)src;
  *(us8*)&tile[r][c0 + 8] = *(const us8*)(src + 8);
  __syncthreads();
  unsigned short* dst = vt + (size_t)bh * 64 * T_SEQ + (size_t)r * T_SEQ + tb * 64 + c0;
  us8 o1, o2;
#pragma unroll
  for (int i = 0; i < 8; ++i) { o1[i] = tile[c0 + i][r]; o2[i] = tile[c0 + 8 + i][r]; }
  *(us8*)dst = o1;
  *(us8*)(dst + 8) = o2;
}

// ------------- 256x256 double-buffered 2-phase GEMM (R7 schedule) + nt stores -------------
#define GK 1024
#define GNT 16   // K / 64

__global__ __launch_bounds__(512, 1) void gemm256(
    const unsigned short* __restrict__ A, const unsigned short* __restrict__ Bt,
    const float* __restrict__ bias, float* __restrict__ Cout, int N, int Mtiles) {
  __shared__ unsigned short As[2][256 * 64];
  __shared__ unsigned short Bs[2][256 * 64];
  int tid = threadIdx.x;
  int lane = tid & 63;
  int wid = tid >> 6;
  int wm = wid >> 2, wn = wid & 3;
  int l16 = lane & 15, g = lane >> 4;
  int swz = l16 & 7;

  int cpx = gridDim.x >> 3;
  int lin = blockIdx.x;
  int wg = (lin & 7) * cpx + (lin >> 3);
  int m0 = (wg % Mtiles) * 256;
  int n0 = (wg / Mtiles) * 256;

  auto stageA2 = [&](int kt, int mh) {
    unsigned short* lds = As[kt & 1];
#pragma unroll
    for (int q = 0; q < 2; ++q) {
      int chunk = q * 512 + tid;
      int rr = chunk >> 3;
      int row = (rr & 63) + ((rr >> 6) << 7) + mh * 64;
      int cpos = chunk & 7;
      int c = cpos ^ (row & 7);
      const unsigned short* src = A + (size_t)(m0 + row) * GK + kt * 64 + c * 8;
      __builtin_amdgcn_global_load_lds(
          (const __attribute__((address_space(1))) void*)src,
          (__attribute__((address_space(3))) void*)(lds + row * 64 + cpos * 8), 16, 0, 0);
    }
  };
  auto stageB4 = [&](int kt) {
    unsigned short* lds = Bs[kt & 1];
#pragma unroll
    for (int q = 0; q < 4; ++q) {
      int chunk = q * 512 + tid;
      int row = chunk >> 3;
      int cpos = chunk & 7;
      int c = cpos ^ (row & 7);
      const unsigned short* src = Bt + (size_t)(n0 + row) * GK + kt * 64 + c * 8;
      __builtin_amdgcn_global_load_lds(
          (const __attribute__((address_space(1))) void*)src,
          (__attribute__((address_space(3))) void*)(lds + row * 64 + cpos * 8), 16, 0, 0);
    }
  };

  stageA2(0, 0); stageB4(0);
  stageA2(0, 1);
  stageA2(1, 0); stageB4(1);
  asm volatile("s_waitcnt vmcnt(8)" ::: "memory");
  asm volatile("s_barrier" ::: "memory");

  f32x4 acc[8][4] = {};

  for (int t = 0; t < GNT; ++t) {
    const char* Ab = (const char*)As[t & 1];
    const char* Bb = (const char*)Bs[t & 1];
    bf16x8 bA[4][2], bB[4][2];

#pragma unroll
    for (int mi = 0; mi < 4; ++mi) {
      int row = wm * 128 + mi * 16 + l16;
#pragma unroll
      for (int kk = 0; kk < 2; ++kk)
        bA[mi][kk] = *(const bf16x8*)(Ab + row * 128 + (((kk * 4 + g) ^ swz) * 16));
    }
#pragma unroll
    for (int ni = 0; ni < 4; ++ni) {
      int row = wn * 64 + ni * 16 + l16;
#pragma unroll
      for (int kk = 0; kk < 2; ++kk)
        bB[ni][kk] = *(const bf16x8*)(Bb + row * 128 + (((kk * 4 + g) ^ swz) * 16));
    }
    if (t + 1 < GNT) stageA2(t + 1, 1);
    asm volatile("s_barrier" ::: "memory");
    asm volatile("s_waitcnt lgkmcnt(0)" ::: "memory");
    __builtin_amdgcn_sched_barrier(0);
    __builtin_amdgcn_s_setprio(1);
#pragma unroll
    for (int mi = 0; mi < 4; ++mi)
#pragma unroll
      for (int ni = 0; ni < 4; ++ni)
#pragma unroll
        for (int kk = 0; kk < 2; ++kk)
          acc[mi][ni] = __builtin_amdgcn_mfma_f32_16x16x32_bf16(bA[mi][kk], bB[ni][kk], acc[mi][ni], 0, 0, 0);
    __builtin_amdgcn_s_setprio(0);
    if (t + 1 < GNT) asm volatile("s_waitcnt vmcnt(8)" ::: "memory");
    else             asm volatile("s_waitcnt vmcnt(0)" ::: "memory");
    asm volatile("s_barrier" ::: "memory");

#pragma unroll
    for (int mi = 0; mi < 4; ++mi) {
      int row = wm * 128 + 64 + mi * 16 + l16;
#pragma unroll
      for (int kk = 0; kk < 2; ++kk)
        bA[mi][kk] = *(const bf16x8*)(Ab + row * 128 + (((kk * 4 + g) ^ swz) * 16));
    }
    if (t + 2 < GNT) { stageA2(t + 2, 0); stageB4(t + 2); }
    asm volatile("s_barrier" ::: "memory");
    asm volatile("s_waitcnt lgkmcnt(0)" ::: "memory");
    __builtin_amdgcn_sched_barrier(0);
    __builtin_amdgcn_s_setprio(1);
#pragma unroll
    for (int mi = 0; mi < 4; ++mi)
#pragma unroll
      for (int ni = 0; ni < 4; ++ni)
#pragma unroll
        for (int kk = 0; kk < 2; ++kk)
          acc[4 + mi][ni] = __builtin_amdgcn_mfma_f32_16x16x32_bf16(bA[mi][kk], bB[ni][kk], acc[4 + mi][ni], 0, 0, 0);
    __builtin_amdgcn_s_setprio(0);
    if (t + 2 < GNT)       asm volatile("s_waitcnt vmcnt(8)" ::: "memory");
    else if (t + 2 == GNT) asm volatile("s_waitcnt vmcnt(2)" ::: "memory");
    asm volatile("s_barrier" ::: "memory");
  }

  // ---- epilogue: bias + f32 NON-TEMPORAL store (output never re-read) ----
#pragma unroll
  for (int mf = 0; mf < 8; ++mf) {
    int row = m0 + wm * 128 + mf * 16 + g * 4;
#pragma unroll
    for (int n = 0; n < 4; ++n) {
      int col = n0 + wn * 64 + n * 16 + l16;
      float bv = bias[col];
#pragma unroll
      for (int j = 0; j < 4; ++j)
        __builtin_nontemporal_store(acc[mf][n][j] + bv, &Cout[(size_t)(row + j) * N + col]);
    }
  }
}

// ------------- MFMA flash attention, bf16 in, DMA-staged, double-buffered -------------
// Softmax in log2 domain: S' = S * (C^-0.5 * log2 e); exp -> exp2 (native v_exp_f32).
__global__ __launch_bounds__(256) void attn_mfma(
    const unsigned short* __restrict__ qkv, const unsigned short* __restrict__ vt,
    unsigned short* __restrict__ y) {
  __shared__ unsigned short Kl[2][4096];
  __shared__ unsigned short Vl[2][4096];
  __shared__ char Pl[8192];

  int bh = blockIdx.y;
  int b = bh >> 4, h = bh & 15;
  int qb = (T_SEQ / 64 - 1) - blockIdx.x;
  int tid = threadIdx.x;
  int lane = tid & 63, w = tid >> 6;
  int l16 = lane & 15, g = lane >> 4;
  size_t bT = (size_t)b * T_SEQ;
  const float scale2 = 0.03125f * 1.44269504f;  // C^-0.5 * log2(e)

  const unsigned short* qrow = qkv + (bT + qb * 64 + w * 16 + l16) * 3072 + h * 64;
  bf16x8 qf[2] = { *(const bf16x8*)(qrow + g * 8), *(const bf16x8*)(qrow + 32 + g * 8) };

  f32x4 yacc[4] = {};
  float mrun[4], lrun[4];
#pragma unroll
  for (int j = 0; j < 4; ++j) { mrun[j] = -3.0e38f; lrun[j] = 0.f; }

  auto stageK = [&](int kb, int buf) {
    const unsigned short* base = qkv + (bT + kb * 64) * 3072 + 1024 + h * 64;
#pragma unroll
    for (int q2 = 0; q2 < 2; ++q2) {
      int chunk = q2 * 256 + tid;
      int row = chunk >> 3, cpos = chunk & 7;
      int c = cpos ^ (row & 7);
      const unsigned short* src = base + (size_t)row * 3072 + c * 8;
      __builtin_amdgcn_global_load_lds(
          (const __attribute__((address_space(1))) void*)src,
          (__attribute__((address_space(3))) void*)&Kl[buf][chunk * 8], 16, 0, 0);
    }
  };
  auto stageV = [&](int kb, int buf) {
    const unsigned short* base = vt + (size_t)bh * 64 * T_SEQ + kb * 64;
#pragma unroll
    for (int q2 = 0; q2 < 2; ++q2) {
      int chunk = q2 * 256 + tid;
      int row = chunk >> 3, cpos = chunk & 7;
      int c = cpos ^ (row & 7);
      const unsigned short* src = base + (size_t)row * T_SEQ + c * 8;
      __builtin_amdgcn_global_load_lds(
          (const __attribute__((address_space(1))) void*)src,
          (__attribute__((address_space(3))) void*)&Vl[buf][chunk * 8], 16, 0, 0);
    }
  };

  stageK(0, 0); stageV(0, 0);

  for (int kb = 0; kb <= qb; ++kb) {
    int buf = kb & 1;
    if (kb < qb) { stageK(kb + 1, buf ^ 1); stageV(kb + 1, buf ^ 1); }
    if (kb < qb) asm volatile("s_waitcnt vmcnt(4)" ::: "memory");
    else         asm volatile("s_waitcnt vmcnt(0)" ::: "memory");
    asm volatile("s_barrier" ::: "memory");

    // ---- S = Q K^T ----
    f32x4 s[4] = {};
#pragma unroll
    for (int kk = 0; kk < 2; ++kk)
#pragma unroll
      for (int n = 0; n < 4; ++n) {
        int krow = n * 16 + l16;
        bf16x8 fb = *(const bf16x8*)((const char*)Kl[buf] + krow * 128 + (((kk * 4 + g) ^ (krow & 7)) * 16));
        s[n] = __builtin_amdgcn_mfma_f32_16x16x32_bf16(qf[kk], fb, s[n], 0, 0, 0);
      }

    // ---- online softmax (log2 domain) ----
    bool diag = (kb == qb);
    float pr[4][4];
    float corr[4];
#pragma unroll
    for (int j = 0; j < 4; ++j) {
      int rloc = w * 16 + g * 4 + j;
      float m = -3.0e38f;
#pragma unroll
      for (int n = 0; n < 4; ++n) {
        float v = s[n][j] * scale2;
        if (diag && (n * 16 + l16) > rloc) v = -3.0e38f;
        pr[n][j] = v;
        m = fmaxf(m, v);
      }
      m = fmaxf(m, __shfl_xor(m, 1));
      m = fmaxf(m, __shfl_xor(m, 2));
      m = fmaxf(m, __shfl_xor(m, 4));
      m = fmaxf(m, __shfl_xor(m, 8));
      float mn = fmaxf(mrun[j], m);
      corr[j] = exp2f(mrun[j] - mn);
      mrun[j] = mn;
      float ps = 0.f;
#pragma unroll
      for (int n = 0; n < 4; ++n) {
        float e = exp2f(pr[n][j] - mn);
        pr[n][j] = e;
        ps += e;
      }
      ps += __shfl_xor(ps, 1);
      ps += __shfl_xor(ps, 2);
      ps += __shfl_xor(ps, 4);
      ps += __shfl_xor(ps, 8);
      lrun[j] = lrun[j] * corr[j] + ps;
    }
#pragma unroll
    for (int n = 0; n < 4; ++n)
#pragma unroll
      for (int j = 0; j < 4; ++j)
        yacc[n][j] *= corr[j];

    // ---- P strip (wave-private rows) ----
#pragma unroll
    for (int j = 0; j < 4; ++j) {
      int row = w * 16 + g * 4 + j;
#pragma unroll
      for (int n = 0; n < 4; ++n)
        *(unsigned short*)(Pl + ((row * 128 + (n * 16 + l16) * 2) ^ ((row & 7) << 4))) = f2bf(pr[n][j]);
    }

    // ---- y += P V ----
#pragma unroll
    for (int kk = 0; kk < 2; ++kk) {
      int prow = w * 16 + l16;
      bf16x8 fa = *(const bf16x8*)(Pl + ((prow * 128 + (kk * 32 + g * 8) * 2) ^ ((prow & 7) << 4)));
#pragma unroll
      for (int n = 0; n < 4; ++n) {
        int vrow = n * 16 + l16;
        bf16x8 fbv = *(const bf16x8*)((const char*)Vl[buf] + vrow * 128 + (((kk * 4 + g) ^ (vrow & 7)) * 16));
        yacc[n] = __builtin_amdgcn_mfma_f32_16x16x32_bf16(fa, fbv, yacc[n], 0, 0, 0);
      }
    }
    asm volatile("s_barrier" ::: "memory");
  }

  // ---- output ----
#pragma unroll
  for (int j = 0; j < 4; ++j) {
    float inv = 1.0f / lrun[j];
    int row = qb * 64 + w * 16 + g * 4 + j;
    unsigned short* yo = y + (bT + row) * C_DIM + h * 64;
#pragma unroll
    for (int n = 0; n < 4; ++n)
      yo[n * 16 + l16] = f2bf(yacc[n][j] * inv);
  }
}

extern "C" void kernel_launch(void* const* d_in, const int* in_sizes, int n_in,
                              void* d_out, int out_size, void* d_ws, size_t ws_size,
                              hipStream_t stream) {
  const int*   x    = (const int*)d_in[0];
  const float* tok  = (const float*)d_in[1];
  const float* pos  = (const float*)d_in[2];
  const float* wq   = (const float*)d_in[3];
  const float* bq   = (const float*)d_in[4];
  const float* wk   = (const float*)d_in[5];
  const float* bk   = (const float*)d_in[6];
  const float* wv   = (const float*)d_in[7];
  const float* bv   = (const float*)d_in[8];
  const float* wh   = (const float*)d_in[9];
  const float* bhd  = (const float*)d_in[10];
  float* out = (float*)d_out;

  char* ws = (char*)d_ws;
  size_t off = 0;
  auto alloc = [&](size_t bytes) {
    void* p = ws + off;
    off += (bytes + 255) & ~(size_t)255;
    return p;
  };
  unsigned short* h_bf    = (unsigned short*)alloc((size_t)4096 * 1024 * 2);
  unsigned short* wqkv_t  = (unsigned short*)alloc((size_t)3072 * 1024 * 2);
  float*          qbias   = (float*)alloc((size_t)3072 * 4);
  unsigned short* wh_t    = (unsigned short*)alloc((size_t)V_DIM * 1024 * 2);
  unsigned short* qkv_bf  = (unsigned short*)alloc((size_t)4096 * 3072 * 2);
  unsigned short* vtb     = (unsigned short*)alloc((size_t)32 * 64 * T_SEQ * 2);
  unsigned short* ybf     = (unsigned short*)alloc((size_t)4096 * 1024 * 2);

  embed_kernel<<<4096, 256, 0, stream>>>(x, tok, pos, h_bf);
  repack_qkv<<<dim3(4096, 3), 256, 0, stream>>>(wq, wk, wv, bq, bk, bv, wqkv_t, qbias);
  repack_whead<<<dim3(V_DIM / 64, 16), 256, 0, stream>>>(wh, wh_t);
  // QKV proj (bf16 out): M=4096 (32 m-tiles, fastest), N=3072 -> 768 blocks
  gemm_bf16_o16<<<768, 256, 0, stream>>>(h_bf, wqkv_t, qbias, qkv_bf, 3072, 32);
  transpose_v<<<dim3(T_SEQ / 64, 2 * H_N), 256, 0, stream>>>(qkv_bf, vtb);
  attn_mfma<<<dim3(T_SEQ / 64, 2 * H_N), 256, 0, stream>>>(qkv_bf, vtb, ybf);
  // head: M=4096, N=32000 -> 2000 blocks
  gemm256<<<2000, 512, 0, stream>>>(ybf, wh_t, bhd, out, V_DIM, 16);
}